// Round 6
// baseline (324.263 us; speedup 1.0000x reference)
//
#include <hip/hip_runtime.h>
#include <hip/hip_bf16.h>

#define T_STEPS 256
#define BATCH   2048
#define INSZ    65
#define HID     64
#define ROWS    8        // 8 batch rows per block -> 256 blocks = 1 block/CU
#define OUTSZ   7
#define NTHREADS 512     // waves 0-3: X-group (input proj), waves 4-7: H-group (recurrence)

typedef __attribute__((ext_vector_type(8))) short bf16x8;  // 8 bf16 = 4 VGPRs
typedef __attribute__((ext_vector_type(4))) float f32x4;

__device__ __forceinline__ short f2bf(float f) {
    union { float f; unsigned u; } v; v.f = f;
    unsigned r = (v.u + 0x7FFFu + ((v.u >> 16) & 1u)) >> 16;  // RNE
    return (short)r;
}
__device__ __forceinline__ float bf2f(short s) {
    union { unsigned u; float f; } v;
    v.u = ((unsigned)(unsigned short)s) << 16;
    return v.f;
}
__device__ __forceinline__ float sigm(float x) {
    return 1.0f / (1.0f + __expf(-x));
}
__device__ __forceinline__ float tanh_f(float x) {
    return 1.0f - 2.0f / (__expf(2.0f * x) + 1.0f);  // saturates at +-1
}

// LDS map (shorts):
//   x slots : [0,768) par0, [768,1536) par1 — K=96 frag-major, elem(row,k) @ (k>>3)*64 + row*8 + (k&7)
//   h slots : [1536,2048) par0, [2048,2560) par1 — K=64, same formula with k=col
// P (separate f32 buffer): raw MFMA C-frag dump, parity p at p*4096;
//   f32x4 of (tile wg, gate gt, lane) @ wg*1024 + gt*256 + lane*4

__global__ __launch_bounds__(NTHREADS, 2)
void lstm_fused(const float* __restrict__ x,    const float* __restrict__ W_ih,
                const float* __restrict__ W_hh, const float* __restrict__ b_ih,
                const float* __restrict__ b_hh, const float* __restrict__ fc_W,
                const float* __restrict__ fc_b, float* __restrict__ out)
{
    __shared__ __align__(16) short Abuf[2560];
    __shared__ __align__(16) float Pbuf[8192];

    const int tid   = threadIdx.x;
    const bool xrole = (tid < 256);
    const int gtid  = xrole ? tid : (tid - 256);  // id within role group
    const int wg    = gtid >> 6;                  // tile: cols [16wg, 16wg+16) of each gate
    const int lane  = gtid & 63;
    const int quad  = lane >> 4;
    const int col16 = lane & 15;
    const int b0    = blockIdx.x * ROWS;

    Abuf[2048 + tid] = 0;                 // h(-1) = 0 (h parity-1 slot)
    if (xrole) {                          // zero x K-pad region k in [64,96) (k=64 re-staged below)
        Abuf[512 + gtid] = 0;
        Abuf[768 + 512 + gtid] = 0;
    }
    __syncthreads();

    // ---------------- role-persistent state ----------------
    bf16x8 wfx[4][3]; f32x4 biasP[4];                       // X: W_ih B-frags (K=96), bias
    int wa0 = 0, wa1 = 0, wa2 = 0; bool has2 = false;
    const float *gp0 = nullptr, *gp1 = nullptr, *gp2 = nullptr;
    float stg[4][3];                                        // X: staged x for steps t+2..t+5
    bf16x8 wfh[4][2];                                       // H: W_hh B-frags (K=64)
    float c_lo = 0.f, c_hi = 0.f;                           // H: cell state (2 rows/lane)
    int hw_lo = 0, hw_hi = 0;

    if (xrole) {
        #pragma unroll
        for (int gt = 0; gt < 4; ++gt) {
            const int n = gt * 64 + wg * 16 + col16;        // gate-major weight row
            #pragma unroll
            for (int kc = 0; kc < 3; ++kc) {
                bf16x8 f;
                #pragma unroll
                for (int j = 0; j < 8; ++j) {
                    const int k = kc * 32 + quad * 8 + j;
                    f[j] = (k < INSZ) ? f2bf(W_ih[n * INSZ + k]) : (short)0;
                }
                wfx[gt][kc] = f;
            }
            const float bv = b_ih[n] + b_hh[n];
            biasP[gt] = (f32x4){bv, bv, bv, bv};
        }
        // staging ownership: 520 elements (8 rows x 65) over 256 threads (2-3 each)
        const int e0 = gtid, e1 = gtid + 256, e2 = gtid + 512;
        const int r0 = e0 / 65, k0 = e0 - r0 * 65;
        const int r1 = e1 / 65, k1 = e1 - r1 * 65;
        has2 = (e2 < ROWS * INSZ);
        const int r2 = has2 ? e2 / 65 : 0, k2 = has2 ? (e2 - (e2 / 65) * 65) : 0;
        wa0 = (k0 >> 3) * 64 + r0 * 8 + (k0 & 7);
        wa1 = (k1 >> 3) * 64 + r1 * 8 + (k1 & 7);
        wa2 = (k2 >> 3) * 64 + r2 * 8 + (k2 & 7);
        gp0 = x + (size_t)(b0 + r0) * T_STEPS * INSZ + k0;
        gp1 = x + (size_t)(b0 + r1) * T_STEPS * INSZ + k1;
        gp2 = x + (size_t)(b0 + r2) * T_STEPS * INSZ + k2;
        // stage x(0) -> slot0, x(1) -> slot1; fill register pipeline x(2..5)
        Abuf[wa0] = f2bf(gp0[0]);
        Abuf[wa1] = f2bf(gp1[0]);
        if (has2) Abuf[wa2] = f2bf(gp2[0]);
        Abuf[768 + wa0] = f2bf(gp0[INSZ]);
        Abuf[768 + wa1] = f2bf(gp1[INSZ]);
        if (has2) Abuf[768 + wa2] = f2bf(gp2[INSZ]);
        #pragma unroll
        for (int i = 0; i < 4; ++i) {
            stg[i][0] = gp0[(2 + i) * INSZ];
            stg[i][1] = gp1[(2 + i) * INSZ];
            stg[i][2] = has2 ? gp2[(2 + i) * INSZ] : 0.f;
        }
    } else {
#if __has_builtin(__builtin_amdgcn_s_setprio)
        __builtin_amdgcn_s_setprio(1);     // H-waves are the critical path
#endif
        #pragma unroll
        for (int gt = 0; gt < 4; ++gt) {
            const int n = gt * 64 + wg * 16 + col16;
            #pragma unroll
            for (int kc = 0; kc < 2; ++kc) {
                bf16x8 f;
                #pragma unroll
                for (int j = 0; j < 8; ++j)
                    f[j] = f2bf(W_hh[n * HID + kc * 32 + quad * 8 + j]);
                wfh[gt][kc] = f;
            }
        }
        // rows activated by this lane: q0:{0,1} q1:{4,5} q2:{2,3} q3:{6,7}
        const int row_lo = (quad & 1) * 4 + (quad & 2);
        const int colg = wg * 16 + col16;
        hw_lo = (colg >> 3) * 64 + row_lo * 8 + (colg & 7);
        hw_hi = hw_lo + 8;
    }
    __syncthreads();

    const int frx  = quad * 64 + (lane & 7) * 8;   // A-frag read base (x/h slots), + kc*256
    const int pofs = wg * 1024 + lane * 4;         // P frag base (floats), + gt*256

    // ---- P(0) = bias + x(0) . W_ih  ->  Pbuf parity 0 ----
    if (xrole) {
        const bf16x8 a0 = *(const bf16x8*)&Abuf[frx];
        const bf16x8 a1 = *(const bf16x8*)&Abuf[frx + 256];
        const bf16x8 a2 = *(const bf16x8*)&Abuf[frx + 512];
        #pragma unroll
        for (int gt = 0; gt < 4; ++gt) {
            f32x4 p = __builtin_amdgcn_mfma_f32_16x16x32_bf16(a0, wfx[gt][0], biasP[gt], 0, 0, 0);
            p = __builtin_amdgcn_mfma_f32_16x16x32_bf16(a1, wfx[gt][1], p, 0, 0, 0);
            p = __builtin_amdgcn_mfma_f32_16x16x32_bf16(a2, wfx[gt][2], p, 0, 0, 0);
            *(f32x4*)&Pbuf[pofs + gt * 256] = p;
        }
    }
    __syncthreads();

    for (int t = 0; t < T_STEPS; t += 4) {
        float ns[4][3];
        if (xrole) {      // batch-load next group's x right after a barrier (age >= 2 steps at use)
            #pragma unroll
            for (int i = 0; i < 4; ++i) {
                const int ts = (t + 6 + i < 255) ? (t + 6 + i) : 255;
                ns[i][0] = gp0[ts * INSZ];
                ns[i][1] = gp1[ts * INSZ];
                ns[i][2] = has2 ? gp2[ts * INSZ] : 0.f;
            }
        }
        #pragma unroll
        for (int i = 0; i < 4; ++i) {      // step t+i, parity par = (t+i)&1
            const int par = i & 1;
            if (xrole) {
                const int ws = par ? 768 : 0;       // x(t+i+2) -> slot par
                Abuf[ws + wa0] = f2bf(stg[i][0]);
                Abuf[ws + wa1] = f2bf(stg[i][1]);
                if (has2) Abuf[ws + wa2] = f2bf(stg[i][2]);
                const int rs = par ? 0 : 768;       // x(t+i+1) frags from slot par^1
                const bf16x8 a0 = *(const bf16x8*)&Abuf[rs + frx];
                const bf16x8 a1 = *(const bf16x8*)&Abuf[rs + frx + 256];
                const bf16x8 a2 = *(const bf16x8*)&Abuf[rs + frx + 512];
                float* pw = &Pbuf[(par ^ 1) * 4096 + pofs];   // P(t+i+1) -> parity par^1
                #pragma unroll
                for (int gt = 0; gt < 4; ++gt) {
                    f32x4 p = __builtin_amdgcn_mfma_f32_16x16x32_bf16(a0, wfx[gt][0], biasP[gt], 0, 0, 0);
                    p = __builtin_amdgcn_mfma_f32_16x16x32_bf16(a1, wfx[gt][1], p, 0, 0, 0);
                    p = __builtin_amdgcn_mfma_f32_16x16x32_bf16(a2, wfx[gt][2], p, 0, 0, 0);
                    *(f32x4*)(pw + gt * 256) = p;
                }
                if (i == 3) {
                    #pragma unroll
                    for (int i2 = 0; i2 < 4; ++i2) {
                        stg[i2][0] = ns[i2][0]; stg[i2][1] = ns[i2][1]; stg[i2][2] = ns[i2][2];
                    }
                }
            } else {
                // gates = P(t+i) [C-operand, layout-identical] + h(t+i-1) . W_hh
                const float* pr = &Pbuf[par * 4096 + pofs];
                f32x4 acc[4];
                #pragma unroll
                for (int gt = 0; gt < 4; ++gt)
                    acc[gt] = *(const f32x4*)(pr + gt * 256);
                const int hs = 1536 + (par ^ 1) * 512;        // h(t+i-1)
                const bf16x8 h0 = *(const bf16x8*)&Abuf[hs + frx];
                const bf16x8 h1 = *(const bf16x8*)&Abuf[hs + frx + 256];
                #pragma unroll
                for (int gt = 0; gt < 4; ++gt) {
                    acc[gt] = __builtin_amdgcn_mfma_f32_16x16x32_bf16(h0, wfh[gt][0], acc[gt], 0, 0, 0);
                    acc[gt] = __builtin_amdgcn_mfma_f32_16x16x32_bf16(h1, wfh[gt][1], acc[gt], 0, 0, 0);
                }
                // dedup: this lane activates rows {row_lo, row_lo+1} = regs {0,1} or {2,3}
                const bool qh = (quad & 2) != 0;
                const float glo0 = qh ? acc[0][2] : acc[0][0], ghi0 = qh ? acc[0][3] : acc[0][1];
                const float glo1 = qh ? acc[1][2] : acc[1][0], ghi1 = qh ? acc[1][3] : acc[1][1];
                const float glo2 = qh ? acc[2][2] : acc[2][0], ghi2 = qh ? acc[2][3] : acc[2][1];
                const float glo3 = qh ? acc[3][2] : acc[3][0], ghi3 = qh ? acc[3][3] : acc[3][1];
                const float il = sigm(glo0), fl = sigm(glo1), gl = tanh_f(glo2), ol = sigm(glo3);
                c_lo = fl * c_lo + il * gl;
                const float hl = ol * tanh_f(c_lo);
                const float ih = sigm(ghi0), fh = sigm(ghi1), gh = tanh_f(ghi2), oh = sigm(ghi3);
                c_hi = fh * c_hi + ih * gh;
                const float hh = oh * tanh_f(c_hi);
                const int hw = 1536 + par * 512;              // h(t+i) -> slot par
                Abuf[hw + hw_lo] = f2bf(hl);
                Abuf[hw + hw_hi] = f2bf(hh);
            }
            __syncthreads();
        }
    }

    // ---- FC(64->7) + sigmoid; h(255) in h parity-1 slot (base 2048) ----
    if (tid < ROWS * OUTSZ) {
        const int m = tid & 7;
        const int o = tid >> 3;
        float s = fc_b[o];
        #pragma unroll
        for (int k = 0; k < HID; ++k)
            s += bf2f(Abuf[2048 + (k >> 3) * 64 + m * 8 + (k & 7)]) * fc_W[o * HID + k];
        out[(size_t)(b0 + m) * OUTSZ + o] = sigm(s);
    }
}

extern "C" void kernel_launch(void* const* d_in, const int* in_sizes, int n_in,
                              void* d_out, int out_size, void* d_ws, size_t ws_size,
                              hipStream_t stream) {
    const float* x    = (const float*)d_in[0];
    const float* W_ih = (const float*)d_in[1];
    const float* W_hh = (const float*)d_in[2];
    const float* b_ih = (const float*)d_in[3];
    const float* b_hh = (const float*)d_in[4];
    const float* fc_W = (const float*)d_in[5];
    const float* fc_b = (const float*)d_in[6];
    float* out = (float*)d_out;

    dim3 grid(BATCH / ROWS);    // 256 blocks -> 1 per CU
    dim3 block(NTHREADS);       // 8 waves: 4 producer (X), 4 consumer (H)
    hipLaunchKernelGGL(lstm_fused, grid, block, 0, stream,
                       x, W_ih, W_hh, b_ih, b_hh, fc_W, fc_b, out);
}